// Round 6
// baseline (425.639 us; speedup 1.0000x reference)
//
#include <hip/hip_runtime.h>
#include <hip/hip_bf16.h>
#include <cstdint>

typedef __bf16 bf16;
typedef __bf16 bf16x4 __attribute__((ext_vector_type(4)));
typedef __bf16 bf16x8 __attribute__((ext_vector_type(8)));
typedef float  f32x4  __attribute__((ext_vector_type(4)));

// XOR-swizzled element offset of 16B chunk `ch` in a 64-elem row (free 2-way).
__device__ __forceinline__ int sw8(int row, int ch)  { return row * 64  + ((ch ^ (row & 7)) << 3); }
// paired-row layout: logical rows R of 32 elems stored as [R/2][64].
__device__ __forceinline__ int swp(int idx, int quad) {
    return (idx >> 1) * 64 + ((((((idx & 1) << 2) + quad)) ^ ((idx >> 1) & 7)) << 3);
}
// pack two f32 into u32 of 2 bf16 (round-half-up: 2 v_add + 1 v_perm)
__device__ __forceinline__ unsigned pk2(float a, float b) {
    unsigned ua = __float_as_uint(a) + 0x8000u;
    unsigned ub = __float_as_uint(b) + 0x8000u;
    return __builtin_amdgcn_perm(ub, ua, 0x07060302u);
}

#define SCALE_C 0.18033688f   // (1/8)*log2(e) — folded into Q at qkv epilogue

// ---------------- stage 1 (fused prep): cast + both transposes --------------
// bid: [0,8192) cast_x | [8192,8448) wz | [8448,9216) transpose_w
__global__ void prep(const float* __restrict__ x, const float* __restrict__ W,
                     const float* __restrict__ Wz, bf16* __restrict__ xb,
                     bf16* __restrict__ wbT, bf16* __restrict__ wzT) {
    __shared__ float tile[64][65];
    const int bid = blockIdx.x;
    const int t = threadIdx.x;
    if (bid < 8192) {                       // cast x -> bf16, float4 loads
        int i = bid * 256 + t;              // 2,097,152 exact
        float4 v = ((const float4*)x)[i];
        bf16x4 o = { (bf16)v.x, (bf16)v.y, (bf16)v.z, (bf16)v.w };
        ((bf16x4*)xb)[i] = o;
    } else if (bid < 8448) {                // Wz[m][j] -> wzT[j][m]
        int o = (bid - 8192) * 256 + t;     // 65,536 exact
        int m = o & 1023, j = o >> 10;
        wzT[o] = (bf16)Wz[m * 64 + j];
    } else {                                // W[hc][d][a] -> wbT[hc*64+a][d]
        int bid4 = bid - 8448;
        int hc = bid4 % 48, d0 = (bid4 / 48) * 64;
        const int a = t & 63, dr = t >> 6;
        #pragma unroll
        for (int i = 0; i < 16; i++) {
            int d = dr + i * 4;
            tile[d][a] = W[(hc * 1024 + d0 + d) * 64 + a];
        }
        __syncthreads();
        const int dc = t & 63, ar = t >> 6;
        #pragma unroll
        for (int i = 0; i < 16; i++) {
            int a2 = ar + i * 4;
            wbT[(hc * 64 + a2) * 1024 + d0 + dc] = (bf16)tile[dc][a2];
        }
    }
}

// ---------------- stage 2: QKV projection GEMM (merged N = 3072) ------------
// BM=128, BN=128, BK=32. Fragments loaded DIRECTLY global->VGPR (each load =
// 16 rows x 64B full cache lines; L1 dedups the wave-pair sharing); no LDS,
// no barriers in the K-loop. LDS (32 KiB cbuf) only for the store epilogue.
__launch_bounds__(256, 4)
__global__ void qkv_gemm(const bf16* __restrict__ xb, const bf16* __restrict__ wbT,
                         bf16* __restrict__ q, bf16* __restrict__ k, bf16* __restrict__ v) {
    const int m0    = blockIdx.x * 128;   // 64 m-tiles
    const int ncol0 = blockIdx.y * 128;   // 24 n-tiles
    const int t = threadIdx.x;
    const int w = t >> 6, l = t & 63;
    const int quad = l >> 4, lan = l & 15;
    const int wm = w & 1, wn = w >> 1;

    __shared__ bf16 cbuf[16384];          // 32 KiB, epilogue only

    f32x4 acc[4][4];
    #pragma unroll
    for (int mi = 0; mi < 4; mi++)
        #pragma unroll
        for (int ni = 0; ni < 4; ni++) acc[mi][ni] = { 0.f, 0.f, 0.f, 0.f };

    const bf16* Arow = xb  + (m0    + wm * 64 + lan) * 1024 + quad * 8;
    const bf16* Brow = wbT + (ncol0 + wn * 64 + lan) * 1024 + quad * 8;

    for (int k0 = 0; k0 < 1024; k0 += 32) {
        bf16x8 af[4], bfr[4];
        #pragma unroll
        for (int mi = 0; mi < 4; mi++)
            af[mi] = *(const bf16x8*)(Arow + mi * 16 * 1024 + k0);
        #pragma unroll
        for (int ni = 0; ni < 4; ni++)
            bfr[ni] = *(const bf16x8*)(Brow + ni * 16 * 1024 + k0);
        #pragma unroll
        for (int mi = 0; mi < 4; mi++)
            #pragma unroll
            for (int ni = 0; ni < 4; ni++)
                acc[mi][ni] = __builtin_amdgcn_mfma_f32_16x16x32_bf16(af[mi], bfr[ni], acc[mi][ni], 0, 0, 0);
    }

    // ---- epilogue phase 1: V -> global direct (b64 along s); Q/K -> cbuf ---
    const int b = m0 >> 10;
    #pragma unroll
    for (int mi = 0; mi < 4; mi++) {
        #pragma unroll
        for (int ni = 0; ni < 4; ni++) {
            int n_base = ncol0 + wn * 64 + ni * 16;       // gate-uniform (16 | 64,192)
            int g = (n_base % 192) >> 6;
            int row0 = wm * 64 + mi * 16 + quad * 4;
            if (g == 2) {
                int h = n_base / 192;
                int a = (n_base & 63) + lan;
                int bh = b * 16 + h;
                int srem = (m0 + row0) & 1023;
                bf16x4 pk = { (bf16)acc[mi][ni][0], (bf16)acc[mi][ni][1],
                              (bf16)acc[mi][ni][2], (bf16)acc[mi][ni][3] };
                *(bf16x4*)(v + (bh * 64 + a) * 1024 + srem) = pk;
            } else {
                float sc = (g == 0) ? SCALE_C : 1.0f;
                int col = wn * 64 + ni * 16 + lan;
                int base = (col & 64) + (col & 7);
                int chs = (col >> 3) & 7;
                #pragma unroll
                for (int r = 0; r < 4; r++) {
                    int row = row0 + r;
                    cbuf[row * 128 + base + ((chs ^ (row & 7)) << 3)] = (bf16)(acc[mi][ni][r] * sc);
                }
            }
        }
    }
    __syncthreads();
    // ---- epilogue phase 2: cbuf -> coalesced b128 Q/K stores ---------------
    #pragma unroll
    for (int i = 0; i < 8; i++) {
        int cc = i * 256 + t;             // 2048 chunks
        int row = cc >> 4, colch = cc & 15;
        int col0 = colch << 3;
        int n = ncol0 + col0;
        int g = (n % 192) >> 6;
        if (g == 2) continue;
        int h = n / 192;
        int a0 = n & 63;
        bf16x8 val = *(const bf16x8*)(cbuf + row * 128 + (col0 & 64) + (((colch & 7) ^ (row & 7)) << 3));
        bf16* dp = (g == 0) ? q : k;
        *(bf16x8*)(dp + ((b * 16 + h) * 1024 + ((m0 + row) & 1023)) * 64 + a0) = val;
    }
}

// ---------------- stage 3: flash attention — fully barrier-free -------------
// grid (128 bh, 8 q-tiles of 128); block 256, wave = 32 q-rows, KV tile 32.
// Q/K/V fragments loaded directly global->VGPR (full-cache-line coalesced;
// the 4 waves read identical K/V tiles -> L1 hits). P round-trips wave-
// private LDS (ds-ordered, no barrier). O stored straight from C-layout regs.
__launch_bounds__(256, 4)
__global__ void attention(const bf16* __restrict__ qg, const bf16* __restrict__ kg,
                          const bf16* __restrict__ vg, bf16* __restrict__ Ocat) {
    const int bh = blockIdx.x;            // 0..127
    const int qt = blockIdx.y;            // 0..7
    const int b = bh >> 4, h = bh & 15;
    const int t = threadIdx.x;
    const int w = t >> 6, l = t & 63;
    const int quad = l >> 4, lan = l & 15;
    const int q0 = qt * 128;

    __shared__ bf16 smem[4096];           // 8 KiB: per-wave P [16][64] paired-row
    bf16* sP = smem + w * 1024;

    // loop-invariant Q fragments (B-operand), direct loads
    const bf16* Qrow = qg + (bh * 1024 + q0 + w * 32 + lan) * 64 + quad * 8;
    bf16x8 qf[2][2];
    #pragma unroll
    for (int kb = 0; kb < 2; kb++)
        #pragma unroll
        for (int qi = 0; qi < 2; qi++)
            qf[kb][qi] = *(const bf16x8*)(Qrow + qi * 16 * 64 + kb * 32);

    const bf16* Krow = kg + (bh * 1024 + lan) * 64 + quad * 8;   // + t0*64 + ti*16*64 + kb*32
    const bf16* Vrow = vg + (bh * 64 + lan) * 1024 + quad * 8;   // + ai*16*1024 + t0

    f32x4 oacc[4][2];
    #pragma unroll
    for (int ai = 0; ai < 4; ai++)
        #pragma unroll
        for (int qi = 0; qi < 2; qi++) oacc[ai][qi] = { 0.f, 0.f, 0.f, 0.f };
    float lsum[2] = { 0.f, 0.f };

    for (int t0 = 0; t0 < 1024; t0 += 32) {
        // S^T = K . Q^T : rows t = ti*16+quad*4+r, cols q = qi*16+lan
        f32x4 sacc[2][2];
        #pragma unroll
        for (int ti = 0; ti < 2; ti++)
            #pragma unroll
            for (int qi = 0; qi < 2; qi++) sacc[ti][qi] = { 0.f, 0.f, 0.f, 0.f };
        #pragma unroll
        for (int kb = 0; kb < 2; kb++) {
            bf16x8 af[2];
            #pragma unroll
            for (int ti = 0; ti < 2; ti++)
                af[ti] = *(const bf16x8*)(Krow + (t0 + ti * 16) * 64 + kb * 32);
            #pragma unroll
            for (int ti = 0; ti < 2; ti++)
                #pragma unroll
                for (int qi = 0; qi < 2; qi++)
                    sacc[ti][qi] = __builtin_amdgcn_mfma_f32_16x16x32_bf16(af[ti], qf[kb][qi], sacc[ti][qi], 0, 0, 0);
        }
        // P = exp2(S) -> paired-row sP[q>>1][...], b64 writes (wave-private)
        #pragma unroll
        for (int ti = 0; ti < 2; ti++) {
            #pragma unroll
            for (int qi = 0; qi < 2; qi++) {
                float p0 = __builtin_amdgcn_exp2f(sacc[ti][qi][0]);
                float p1 = __builtin_amdgcn_exp2f(sacc[ti][qi][1]);
                float p2 = __builtin_amdgcn_exp2f(sacc[ti][qi][2]);
                float p3 = __builtin_amdgcn_exp2f(sacc[ti][qi][3]);
                lsum[qi] += (p0 + p1) + (p2 + p3);
                int ql = qi * 16 + lan;
                int chl = (ql & 1) * 4 + ti * 2 + (quad >> 1);
                uint2 pk = { pk2(p0, p1), pk2(p2, p3) };
                *(uint2*)(sP + (ql >> 1) * 64 + ((chl ^ ((ql >> 1) & 7)) << 3) + (quad & 1) * 4) = pk;
            }
        }
        // O^T += V^T . P^T  (k = t, 32); V frags direct, P from wave-LDS
        bf16x8 bp[2];
        #pragma unroll
        for (int qi = 0; qi < 2; qi++)
            bp[qi] = *(const bf16x8*)(sP + swp(qi * 16 + lan, quad));
        #pragma unroll
        for (int ai = 0; ai < 4; ai++) {
            bf16x8 av = *(const bf16x8*)(Vrow + ai * 16 * 1024 + t0);
            #pragma unroll
            for (int qi = 0; qi < 2; qi++)
                oacc[ai][qi] = __builtin_amdgcn_mfma_f32_16x16x32_bf16(av, bp[qi], oacc[ai][qi], 0, 0, 0);
        }
    }

    // row sums: reduce quad partials (lanes lan, lan+16, lan+32, lan+48)
    float rinv[2];
    #pragma unroll
    for (int qi = 0; qi < 2; qi++) {
        float s = lsum[qi];
        s += __shfl_xor(s, 16);
        s += __shfl_xor(s, 32);
        rinv[qi] = 1.f / s;
    }
    // store normalized O directly from C-layout: lane holds a = ai*16+quad*4+r
    // for q = qi*16+lan -> bf16x4 (8B) stores; L2 merges lines.
    #pragma unroll
    for (int ai = 0; ai < 4; ai++) {
        #pragma unroll
        for (int qi = 0; qi < 2; qi++) {
            unsigned lo = pk2(oacc[ai][qi][0] * rinv[qi], oacc[ai][qi][1] * rinv[qi]);
            unsigned hi = pk2(oacc[ai][qi][2] * rinv[qi], oacc[ai][qi][3] * rinv[qi]);
            uint2 ok = { lo, hi };
            int s2 = q0 + w * 32 + qi * 16 + lan;
            *(uint2*)(Ocat + (b * 1024 + s2) * 1024 + h * 64 + ai * 16 + quad * 4) = ok;
        }
    }
}

// ---------------- stage 4: out = Ocat[8192x1024] @ Wz (via wzT[j][m]) -------
// BM=16, grid 512 (2 blocks/CU); barrier-free, LDS-free direct fragment loads.
__launch_bounds__(256, 4)
__global__ void zgemm(const bf16* __restrict__ Ocat, const bf16* __restrict__ wzT,
                      float* __restrict__ out) {
    const int m0 = blockIdx.x * 16;
    const int t = threadIdx.x;
    const int w = t >> 6, l = t & 63;
    const int quad = l >> 4, lan = l & 15;

    f32x4 acc = { 0.f, 0.f, 0.f, 0.f };
    const bf16* Arow = Ocat + (m0 + lan) * 1024 + quad * 8;
    const bf16* Brow = wzT + (w * 16 + lan) * 1024 + quad * 8;

    for (int k0 = 0; k0 < 1024; k0 += 32) {
        bf16x8 af = *(const bf16x8*)(Arow + k0);
        bf16x8 bfr = *(const bf16x8*)(Brow + k0);
        acc = __builtin_amdgcn_mfma_f32_16x16x32_bf16(af, bfr, acc, 0, 0, 0);
    }
    #pragma unroll
    for (int r = 0; r < 4; r++)
        out[(m0 + quad * 4 + r) * 64 + w * 16 + lan] = acc[r];
}

// ---------------- launch ----------------------------------------------------
extern "C" void kernel_launch(void* const* d_in, const int* in_sizes, int n_in,
                              void* d_out, int out_size, void* d_ws, size_t ws_size,
                              hipStream_t stream) {
    const float* x  = (const float*)d_in[0];   // [8,1024,1024]
    const float* W  = (const float*)d_in[1];   // [16,3,1024,64]
    const float* Wz = (const float*)d_in[2];   // [1024,64]
    float* out = (float*)d_out;                // [8,1024,64]

    bf16* ws  = (bf16*)d_ws;
    bf16* xb  = ws;                 // 8,388,608  (reused as Ocat after qkv)
    bf16* wbT = xb  + 8388608;      // 3,145,728
    bf16* wzT = wbT + 3145728;      //    65,536
    bf16* qb  = wzT + 65536;        // 8,388,608
    bf16* kb  = qb  + 8388608;      // 8,388,608
    bf16* vb  = kb  + 8388608;      // 8,388,608   (total ~70 MiB)
    bf16* Ocat = xb;                // xb dead after qkv_gemm

    prep      <<<9216, 256, 0, stream>>>(x, W, Wz, xb, wbT, wzT);
    qkv_gemm  <<<dim3(64, 24), 256, 0, stream>>>(xb, wbT, qb, kb, vb);
    attention <<<dim3(128, 8), 256, 0, stream>>>(qb, kb, vb, Ocat);
    zgemm     <<<512, 256, 0, stream>>>(Ocat, wzT, out);
}

// Round 7
// 196.499 us; speedup vs baseline: 2.1661x; 2.1661x over previous
//
#include <hip/hip_runtime.h>
#include <hip/hip_bf16.h>
#include <cstdint>

typedef __bf16 bf16;
typedef __bf16 bf16x4 __attribute__((ext_vector_type(4)));
typedef __bf16 bf16x8 __attribute__((ext_vector_type(8)));
typedef float  f32x4  __attribute__((ext_vector_type(4)));

// async global->LDS, 16B per lane. LDS dst must be wave-uniform base + lane*16.
__device__ __forceinline__ void async_ld16(const bf16* g, bf16* l) {
    __builtin_amdgcn_global_load_lds(
        (const __attribute__((address_space(1))) unsigned int*)g,
        (__attribute__((address_space(3)))       unsigned int*)l,
        16, 0, 0);
}

// XOR-swizzled element offset of 16B chunk `ch` in a 64-elem row (free 2-way).
__device__ __forceinline__ int sw8(int row, int ch)  { return row * 64  + ((ch ^ (row & 7)) << 3); }
// paired-row layout: logical rows R of 32 elems stored as [R/2][64].
__device__ __forceinline__ int swp(int idx, int quad) {
    return (idx >> 1) * 64 + ((((((idx & 1) << 2) + quad)) ^ ((idx >> 1) & 7)) << 3);
}
// pack two f32 into u32 of 2 bf16 (round-half-up: 2 v_add + 1 v_perm)
__device__ __forceinline__ unsigned pk2(float a, float b) {
    unsigned ua = __float_as_uint(a) + 0x8000u;
    unsigned ub = __float_as_uint(b) + 0x8000u;
    return __builtin_amdgcn_perm(ub, ua, 0x07060302u);
}

#define SCALE_C 0.18033688f   // (1/8)*log2(e) — folded into Q at qkv epilogue

// ---------------- stage 1 (fused prep): cast + both transposes --------------
// bid: [0,8192) cast_x | [8192,8448) wz | [8448,9216) transpose_w
__global__ void prep(const float* __restrict__ x, const float* __restrict__ W,
                     const float* __restrict__ Wz, bf16* __restrict__ xb,
                     bf16* __restrict__ wbT, bf16* __restrict__ wzT) {
    __shared__ float tile[64][65];
    const int bid = blockIdx.x;
    const int t = threadIdx.x;
    if (bid < 8192) {                       // cast x -> bf16, float4 loads
        int i = bid * 256 + t;              // 2,097,152 exact
        float4 v = ((const float4*)x)[i];
        bf16x4 o = { (bf16)v.x, (bf16)v.y, (bf16)v.z, (bf16)v.w };
        ((bf16x4*)xb)[i] = o;
    } else if (bid < 8448) {                // Wz[m][j] -> wzT[j][m]
        int o = (bid - 8192) * 256 + t;     // 65,536 exact
        int m = o & 1023, j = o >> 10;
        wzT[o] = (bf16)Wz[m * 64 + j];
    } else {                                // W[hc][d][a] -> wbT[hc*64+a][d]
        int bid4 = bid - 8448;
        int hc = bid4 % 48, d0 = (bid4 / 48) * 64;
        const int a = t & 63, dr = t >> 6;
        #pragma unroll
        for (int i = 0; i < 16; i++) {
            int d = dr + i * 4;
            tile[d][a] = W[(hc * 1024 + d0 + d) * 64 + a];
        }
        __syncthreads();
        const int dc = t & 63, ar = t >> 6;
        #pragma unroll
        for (int i = 0; i < 16; i++) {
            int a2 = ar + i * 4;
            wbT[(hc * 64 + a2) * 1024 + d0 + dc] = (bf16)tile[dc][a2];
        }
    }
}

// ---------------- stage 2: QKV projection GEMM (merged N = 3072) ------------
// PROVEN R3/R4 structure: BM=128, BN=128, BK=64, single-buffer 2-barrier,
// LDS-staged fragments (fragments MUST come from LDS — R6 lesson).
__launch_bounds__(256, 3)
__global__ void qkv_gemm(const bf16* __restrict__ xb, const bf16* __restrict__ wbT,
                         bf16* __restrict__ q, bf16* __restrict__ k, bf16* __restrict__ v) {
    const int m0    = blockIdx.x * 128;
    const int ncol0 = blockIdx.y * 128;
    const int t = threadIdx.x;
    const int w = t >> 6, l = t & 63;
    const int quad = l >> 4, lan = l & 15;
    const int wm = w & 1, wn = w >> 1;

    __shared__ bf16 smem[16384];          // 32 KiB
    bf16* sA = smem;                      // [128][64] sw8
    bf16* sB = smem + 8192;               // [128][64] sw8

    f32x4 acc[4][4];
    #pragma unroll
    for (int mi = 0; mi < 4; mi++)
        #pragma unroll
        for (int ni = 0; ni < 4; ni++) acc[mi][ni] = { 0.f, 0.f, 0.f, 0.f };

    const bf16* Ag = xb  + m0 * 1024;
    const bf16* Bg = wbT + ncol0 * 1024;

    for (int k0 = 0; k0 < 1024; k0 += 64) {
        #pragma unroll
        for (int i = 0; i < 4; i++) {
            int cidx = i * 256 + t;
            int r = cidx >> 3, ch = (cidx & 7) ^ (r & 7);
            async_ld16(Ag + r * 1024 + k0 + ch * 8, sA + cidx * 8);
        }
        #pragma unroll
        for (int i = 0; i < 4; i++) {
            int cidx = i * 256 + t;
            int r = cidx >> 3, ch = (cidx & 7) ^ (r & 7);
            async_ld16(Bg + r * 1024 + k0 + ch * 8, sB + cidx * 8);
        }
        __syncthreads();
        #pragma unroll
        for (int kb = 0; kb < 2; kb++) {
            bf16x8 af[4], bfr[4];
            #pragma unroll
            for (int mi = 0; mi < 4; mi++)
                af[mi] = *(const bf16x8*)(sA + sw8(wm * 64 + mi * 16 + lan, kb * 4 + quad));
            #pragma unroll
            for (int ni = 0; ni < 4; ni++)
                bfr[ni] = *(const bf16x8*)(sB + sw8(wn * 64 + ni * 16 + lan, kb * 4 + quad));
            #pragma unroll
            for (int mi = 0; mi < 4; mi++)
                #pragma unroll
                for (int ni = 0; ni < 4; ni++)
                    acc[mi][ni] = __builtin_amdgcn_mfma_f32_16x16x32_bf16(af[mi], bfr[ni], acc[mi][ni], 0, 0, 0);
        }
        __syncthreads();
    }

    // ---- epilogue phase 1: V -> global direct (b64 along s); Q/K -> cbuf ---
    bf16* cbuf = smem;                    // [128 rows][128 cols], sw8 per 64-half
    const int b = m0 >> 10;
    #pragma unroll
    for (int mi = 0; mi < 4; mi++) {
        #pragma unroll
        for (int ni = 0; ni < 4; ni++) {
            int n_base = ncol0 + wn * 64 + ni * 16;       // gate-uniform (16 | 64,192)
            int g = (n_base % 192) >> 6;
            int row0 = wm * 64 + mi * 16 + quad * 4;
            if (g == 2) {
                int h = n_base / 192;
                int a = (n_base & 63) + lan;
                int bh = b * 16 + h;
                int srem = (m0 + row0) & 1023;
                bf16x4 pk = { (bf16)acc[mi][ni][0], (bf16)acc[mi][ni][1],
                              (bf16)acc[mi][ni][2], (bf16)acc[mi][ni][3] };
                *(bf16x4*)(v + (bh * 64 + a) * 1024 + srem) = pk;
            } else {
                float sc = (g == 0) ? SCALE_C : 1.0f;
                int col = wn * 64 + ni * 16 + lan;
                int base = (col & 64) + (col & 7);
                int chs = (col >> 3) & 7;
                #pragma unroll
                for (int r = 0; r < 4; r++) {
                    int row = row0 + r;
                    cbuf[row * 128 + base + ((chs ^ (row & 7)) << 3)] = (bf16)(acc[mi][ni][r] * sc);
                }
            }
        }
    }
    __syncthreads();
    // ---- epilogue phase 2: cbuf -> coalesced b128 Q/K stores ---------------
    #pragma unroll
    for (int i = 0; i < 8; i++) {
        int cc = i * 256 + t;             // 2048 chunks
        int row = cc >> 4, colch = cc & 15;
        int col0 = colch << 3;
        int n = ncol0 + col0;
        int g = (n % 192) >> 6;
        if (g == 2) continue;
        int h = n / 192;
        int a0 = n & 63;
        bf16x8 val = *(const bf16x8*)(cbuf + row * 128 + (col0 & 64) + (((colch & 7) ^ (row & 7)) << 3));
        bf16* dp = (g == 0) ? q : k;
        *(bf16x8*)(dp + ((b * 16 + h) * 1024 + ((m0 + row) & 1023)) * 64 + a0) = val;
    }
}

// ---------------- stage 3: flash attention, q-tile 64/wave ------------------
// grid (128 bh, 4 q-tiles of 256); block 256 (4 waves x 64 q-rows).
// KV tile 32, double-buffered; per-iter: 32 MFMA vs constant K/V fragment +
// staging traffic -> MFMA-bound. Q fragments direct-loaded once (regs).
// LDS 32 KiB -> 3 blocks/CU (VGPR-capped), grid 512 = single round.
__launch_bounds__(256, 3)
__global__ void attention(const bf16* __restrict__ qg, const bf16* __restrict__ kg,
                          const bf16* __restrict__ vg, bf16* __restrict__ Ocat) {
    const int bh = blockIdx.x;            // 0..127
    const int qt = blockIdx.y;            // 0..3
    const int b = bh >> 4, h = bh & 15;
    const int t = threadIdx.x;
    const int w = t >> 6, l = t & 63;
    const int quad = l >> 4, lan = l & 15;
    const int q0 = qt * 256;

    __shared__ bf16 smem[16384];          // 32 KiB
    // dbuf: buf0 [0,4096): K[0,2048) V[2048,4096); buf1 [4096,8192)
    bf16* sP = smem + 8192 + w * 2048;    // per-wave P [64 q][32 t] paired-row (4 KiB)

    // loop-invariant Q fragments (B-operand), one-time direct loads
    const bf16* Qrow = qg + (bh * 1024 + q0 + w * 64 + lan) * 64 + quad * 8;
    bf16x8 qf[2][4];
    #pragma unroll
    for (int kb = 0; kb < 2; kb++)
        #pragma unroll
        for (int qi = 0; qi < 4; qi++)
            qf[kb][qi] = *(const bf16x8*)(Qrow + qi * 16 * 64 + kb * 32);

    const bf16* Kg = kg + bh * 65536;
    const bf16* Vg = vg + bh * 65536;

    // stage K[32t][64d] (sw8 rows) + V^T[64a][32t] (paired-row) into buf
    auto stageKV = [&](int t0, bf16* buf) {
        {   int c = t, row = c >> 3, ch = (c & 7) ^ (row & 7);
            async_ld16(Kg + (t0 + row) * 64 + ch * 8, buf + c * 8); }
        {   int c = t, row = c >> 3, ch = (c & 7) ^ (row & 7);
            int a = row * 2 + (ch >> 2), tl = (ch & 3) * 8;
            async_ld16(Vg + a * 1024 + t0 + tl, buf + 2048 + c * 8); }
    };

    f32x4 oacc[4][4];
    #pragma unroll
    for (int ai = 0; ai < 4; ai++)
        #pragma unroll
        for (int qi = 0; qi < 4; qi++) oacc[ai][qi] = { 0.f, 0.f, 0.f, 0.f };
    float lsum[4] = { 0.f, 0.f, 0.f, 0.f };

    stageKV(0, smem);
    for (int it = 0; it < 32; it++) {
        __syncthreads();                  // buf[it&1] staged; other buf free
        if (it < 31) stageKV((it + 1) * 32, smem + ((it + 1) & 1) * 4096);
        bf16* bK = smem + (it & 1) * 4096;
        bf16* bV = bK + 2048;

        // S^T = K . Q^T : rows t = ti*16+quad*4+r, cols q = qi*16+lan
        f32x4 sacc[2][4];
        #pragma unroll
        for (int ti = 0; ti < 2; ti++)
            #pragma unroll
            for (int qi = 0; qi < 4; qi++) sacc[ti][qi] = { 0.f, 0.f, 0.f, 0.f };
        #pragma unroll
        for (int kb = 0; kb < 2; kb++) {
            bf16x8 af[2];
            #pragma unroll
            for (int ti = 0; ti < 2; ti++)
                af[ti] = *(const bf16x8*)(bK + sw8(ti * 16 + lan, kb * 4 + quad));
            #pragma unroll
            for (int ti = 0; ti < 2; ti++)
                #pragma unroll
                for (int qi = 0; qi < 4; qi++)
                    sacc[ti][qi] = __builtin_amdgcn_mfma_f32_16x16x32_bf16(af[ti], qf[kb][qi], sacc[ti][qi], 0, 0, 0);
        }
        // P = exp2(S) -> paired-row sP (wave-private, ds-ordered: no barrier)
        #pragma unroll
        for (int ti = 0; ti < 2; ti++) {
            #pragma unroll
            for (int qi = 0; qi < 4; qi++) {
                float p0 = __builtin_amdgcn_exp2f(sacc[ti][qi][0]);
                float p1 = __builtin_amdgcn_exp2f(sacc[ti][qi][1]);
                float p2 = __builtin_amdgcn_exp2f(sacc[ti][qi][2]);
                float p3 = __builtin_amdgcn_exp2f(sacc[ti][qi][3]);
                lsum[qi] += (p0 + p1) + (p2 + p3);
                int ql = qi * 16 + lan;
                int chl = (ql & 1) * 4 + ti * 2 + (quad >> 1);
                uint2 pk = { pk2(p0, p1), pk2(p2, p3) };
                *(uint2*)(sP + (ql >> 1) * 64 + ((chl ^ ((ql >> 1) & 7)) << 3) + (quad & 1) * 4) = pk;
            }
        }
        // O^T += V^T . P^T  (k = t, 32): one k-step
        bf16x8 bp[4];
        #pragma unroll
        for (int qi = 0; qi < 4; qi++)
            bp[qi] = *(const bf16x8*)(sP + swp(qi * 16 + lan, quad));
        #pragma unroll
        for (int ai = 0; ai < 4; ai++) {
            bf16x8 av = *(const bf16x8*)(bV + swp(ai * 16 + lan, quad));
            #pragma unroll
            for (int qi = 0; qi < 4; qi++)
                oacc[ai][qi] = __builtin_amdgcn_mfma_f32_16x16x32_bf16(av, bp[qi], oacc[ai][qi], 0, 0, 0);
        }
    }

    // row sums: reduce quad partials (lanes lan, +16, +32, +48)
    float rinv[4];
    #pragma unroll
    for (int qi = 0; qi < 4; qi++) {
        float s = lsum[qi];
        s += __shfl_xor(s, 16);
        s += __shfl_xor(s, 32);
        rinv[qi] = 1.f / s;
    }
    // store normalized O directly from C-layout: lane holds a = ai*16+quad*4+r
    // for q = qi*16+lan -> 8B stores; L2 merges lines.
    #pragma unroll
    for (int ai = 0; ai < 4; ai++) {
        #pragma unroll
        for (int qi = 0; qi < 4; qi++) {
            uint2 ok = { pk2(oacc[ai][qi][0] * rinv[qi], oacc[ai][qi][1] * rinv[qi]),
                         pk2(oacc[ai][qi][2] * rinv[qi], oacc[ai][qi][3] * rinv[qi]) };
            int s2 = q0 + w * 64 + qi * 16 + lan;
            *(uint2*)(Ocat + (b * 1024 + s2) * 1024 + h * 64 + ai * 16 + quad * 4) = ok;
        }
    }
}

// ---------------- stage 4: out = Ocat[8192x1024] @ Wz (via wzT[j][m]) -------
// BM=32, N=64, BK=64, 256 blocks; double-buffered LDS pipeline (R5-proven).
__launch_bounds__(256, 4)
__global__ void zgemm(const bf16* __restrict__ Ocat, const bf16* __restrict__ wzT,
                      float* __restrict__ out) {
    const int m0 = blockIdx.x * 32;
    const int t = threadIdx.x;
    const int w = t >> 6, l = t & 63;
    const int quad = l >> 4, lan = l & 15;

    __shared__ bf16 smem[12288];          // buf: A[32x64]=2048 + B[64x64]=4096; x2

    f32x4 acc[2];
    acc[0] = { 0.f, 0.f, 0.f, 0.f };
    acc[1] = { 0.f, 0.f, 0.f, 0.f };

    auto stage = [&](int k0, bf16* buf) {
        {   int c = t, row = c >> 3, ch = (c & 7) ^ (row & 7);
            async_ld16(Ocat + (m0 + row) * 1024 + k0 + ch * 8, buf + c * 8); }
        #pragma unroll
        for (int i = 0; i < 2; i++) {
            int c = i * 256 + t, row = c >> 3, ch = (c & 7) ^ (row & 7);
            async_ld16(wzT + row * 1024 + k0 + ch * 8, buf + 2048 + c * 8);
        }
    };

    stage(0, smem);
    for (int it = 0; it < 16; it++) {
        __syncthreads();
        if (it < 15) stage((it + 1) * 64, smem + ((it + 1) & 1) * 6144);
        bf16* bufA = smem + (it & 1) * 6144;
        bf16* bufB = bufA + 2048;
        #pragma unroll
        for (int kb = 0; kb < 2; kb++) {
            bf16x8 bfr = *(const bf16x8*)(bufB + sw8(w * 16 + lan, kb * 4 + quad));
            #pragma unroll
            for (int mi = 0; mi < 2; mi++) {
                bf16x8 af = *(const bf16x8*)(bufA + sw8(mi * 16 + lan, kb * 4 + quad));
                acc[mi] = __builtin_amdgcn_mfma_f32_16x16x32_bf16(af, bfr, acc[mi], 0, 0, 0);
            }
        }
    }
    #pragma unroll
    for (int mi = 0; mi < 2; mi++)
        #pragma unroll
        for (int r = 0; r < 4; r++)
            out[(m0 + mi * 16 + quad * 4 + r) * 64 + w * 16 + lan] = acc[mi][r];
}

// ---------------- launch ----------------------------------------------------
extern "C" void kernel_launch(void* const* d_in, const int* in_sizes, int n_in,
                              void* d_out, int out_size, void* d_ws, size_t ws_size,
                              hipStream_t stream) {
    const float* x  = (const float*)d_in[0];   // [8,1024,1024]
    const float* W  = (const float*)d_in[1];   // [16,3,1024,64]
    const float* Wz = (const float*)d_in[2];   // [1024,64]
    float* out = (float*)d_out;                // [8,1024,64]

    bf16* ws  = (bf16*)d_ws;
    bf16* xb  = ws;                 // 8,388,608  (reused as Ocat after qkv)
    bf16* wbT = xb  + 8388608;      // 3,145,728
    bf16* wzT = wbT + 3145728;      //    65,536
    bf16* qb  = wzT + 65536;        // 8,388,608
    bf16* kb  = qb  + 8388608;      // 8,388,608
    bf16* vb  = kb  + 8388608;      // 8,388,608   (total ~70 MiB)
    bf16* Ocat = xb;                // xb dead after qkv_gemm

    prep      <<<9216, 256, 0, stream>>>(x, W, Wz, xb, wbT, wzT);
    qkv_gemm  <<<dim3(64, 24), 256, 0, stream>>>(xb, wbT, qb, kb, vb);
    attention <<<dim3(128, 4), 256, 0, stream>>>(qb, kb, vb, Ocat);
    zgemm     <<<256, 256, 0, stream>>>(Ocat, wzT, out);
}